// Round 1
// baseline (305.325 us; speedup 1.0000x reference)
//
#include <hip/hip_runtime.h>
#include <hip/hip_bf16.h>

// HyperbolicContrastiveLoss: N=8192, D=512, f32 in, scalar f32 out.
// loss = (1/2N) * sum_i [ log(sum_j exp(sim_ij)) + log(sum_i' exp(sim_i'j=i)) - 2*sim_ii ]
// sim bounded in [-~3.5, 0] -> no max shift needed for logsumexp.

#define NROWS 8192
#define DDIM  512
#define BM 128
#define BN 128
#define BK 64

typedef __attribute__((ext_vector_type(8))) short bf16x8;
typedef __attribute__((ext_vector_type(4))) float f32x4;

constexpr float EPSF = 1e-10f;

__device__ inline unsigned short f2bf(float f) {
    union { float f; unsigned int u; } x; x.f = f;
    unsigned int r = x.u + 0x7fffu + ((x.u >> 16) & 1u);  // RNE
    return (unsigned short)(r >> 16);
}

// One wave per row: convert f32 -> bf16 and compute row squared norm.
__global__ __launch_bounds__(256) void convert_norms(const float* __restrict__ src,
                                                     unsigned short* __restrict__ dst,
                                                     float* __restrict__ nrm) {
    int wave = threadIdx.x >> 6;
    int lane = threadIdx.x & 63;
    int row  = blockIdx.x * 4 + wave;
    const float* r = src + (size_t)row * DDIM + lane * 8;
    float4 v0 = *(const float4*)(r);
    float4 v1 = *(const float4*)(r + 4);
    float ss = v0.x*v0.x + v0.y*v0.y + v0.z*v0.z + v0.w*v0.w
             + v1.x*v1.x + v1.y*v1.y + v1.z*v1.z + v1.w*v1.w;
    unsigned short u[8];
    u[0]=f2bf(v0.x); u[1]=f2bf(v0.y); u[2]=f2bf(v0.z); u[3]=f2bf(v0.w);
    u[4]=f2bf(v1.x); u[5]=f2bf(v1.y); u[6]=f2bf(v1.z); u[7]=f2bf(v1.w);
    *(uint4*)(dst + (size_t)row * DDIM + lane * 8) = *(const uint4*)u;
    for (int m = 1; m < 64; m <<= 1) ss += __shfl_xor(ss, m);
    if (lane == 0) nrm[row] = ss;
}

// 128x128 tile MFMA GEMM (A@B^T) with fused hyperbolic-sim epilogue.
// Block = 256 threads (4 waves, 2x2), each wave 64x64 = 4x4 frags of 16x16x32.
__global__ __launch_bounds__(256) void hyper_gemm(
    const unsigned short* __restrict__ A, const unsigned short* __restrict__ B,
    const float* __restrict__ a2, const float* __restrict__ b2,
    float* __restrict__ rowsum, float* __restrict__ colsum,
    float* __restrict__ diag) {

    __shared__ unsigned short As[BM * BK];
    __shared__ unsigned short Bs[BN * BK];

    const int tid  = threadIdx.x;
    const int lane = tid & 63;
    const int w    = tid >> 6;
    const int wr   = w >> 1, wc = w & 1;
    const int i0 = blockIdx.y * BM;
    const int j0 = blockIdx.x * BN;
    const int g  = lane >> 4;      // 0..3
    const int cl = lane & 15;      // 0..15

    f32x4 acc[4][4];
    for (int mi = 0; mi < 4; ++mi)
        for (int ni = 0; ni < 4; ++ni)
            acc[mi][ni] = (f32x4)0.0f;

    for (int k0 = 0; k0 < DDIM; k0 += BK) {
        __syncthreads();
        // stage A,B tiles: 128x64 bf16 each; XOR-swizzle byte ^= ((row&7)<<4)
        #pragma unroll
        for (int c = 0; c < 4; ++c) {
            int idx  = c * 256 + tid;        // chunk id 0..1023
            int row  = idx >> 3;             // 0..127
            int cwb  = (idx & 7) * 16;       // byte col within row (128B rows)
            int boff = row * 128 + (cwb ^ ((row & 7) << 4));
            const uint4 va = *(const uint4*)(A + (size_t)(i0 + row) * DDIM + k0 + (idx & 7) * 8);
            *(uint4*)((char*)As + boff) = va;
            const uint4 vb = *(const uint4*)(B + (size_t)(j0 + row) * DDIM + k0 + (idx & 7) * 8);
            *(uint4*)((char*)Bs + boff) = vb;
        }
        __syncthreads();

        #pragma unroll
        for (int kk = 0; kk < BK; kk += 32) {
            bf16x8 af[4], bfr[4];
            int cb = (kk + g * 8) * 2;       // byte offset of this lane's 8 k-elems
            #pragma unroll
            for (int mi = 0; mi < 4; ++mi) {
                int row = wr * 64 + mi * 16 + cl;
                af[mi] = *(const bf16x8*)((const char*)As + row * 128 + (cb ^ ((row & 7) << 4)));
            }
            #pragma unroll
            for (int ni = 0; ni < 4; ++ni) {
                int row = wc * 64 + ni * 16 + cl;
                bfr[ni] = *(const bf16x8*)((const char*)Bs + row * 128 + (cb ^ ((row & 7) << 4)));
            }
            #pragma unroll
            for (int mi = 0; mi < 4; ++mi)
                #pragma unroll
                for (int ni = 0; ni < 4; ++ni)
                    acc[mi][ni] = __builtin_amdgcn_mfma_f32_16x16x32_bf16(af[mi], bfr[ni], acc[mi][ni], 0, 0, 0);
        }
    }

    // Epilogue: sim + exp, accumulate row/col partials.
    float B2c[4], omb[4];
    #pragma unroll
    for (int ni = 0; ni < 4; ++ni) {
        float B2 = b2[j0 + wc * 64 + ni * 16 + cl];
        B2c[ni] = B2;
        omb[ni] = 1.0f - fminf(B2, 1.0f - EPSF);
    }

    float rp[4][4];   // [mi][reg] row partials
    float cp[4] = {0.f, 0.f, 0.f, 0.f};
    #pragma unroll
    for (int mi = 0; mi < 4; ++mi) {
        #pragma unroll
        for (int reg = 0; reg < 4; ++reg) {
            int   gi  = i0 + wr * 64 + mi * 16 + g * 4 + reg;
            float A2  = a2[gi];
            float oma = 1.0f - fminf(A2, 1.0f - EPSF);
            float rsum = 0.f;
            #pragma unroll
            for (int ni = 0; ni < 4; ++ni) {
                int   gj   = j0 + wc * 64 + ni * 16 + cl;
                float dot  = acc[mi][ni][reg];
                float diff = A2 + B2c[ni] - 2.0f * dot;
                float den  = fmaxf(oma * omb[ni], EPSF);
                float arg  = fmaxf(1.0f + 2.0f * diff / den, 1.0f + EPSF);
                float dist = logf(arg + sqrtf(arg * arg - 1.0f));   // arccosh
                float sim  = -dist;
                if (gi == gj) diag[gi] = sim;
                float e = __expf(sim);
                rsum += e;
                cp[ni] += e;
            }
            rp[mi][reg] = rsum;
        }
    }

    // row sums: reduce across the 16 lanes sharing (lane>>4)
    #pragma unroll
    for (int mi = 0; mi < 4; ++mi)
        #pragma unroll
        for (int reg = 0; reg < 4; ++reg) {
            float v = rp[mi][reg];
            v += __shfl_xor(v, 1); v += __shfl_xor(v, 2);
            v += __shfl_xor(v, 4); v += __shfl_xor(v, 8);
            if (cl == 0) atomicAdd(&rowsum[i0 + wr * 64 + mi * 16 + g * 4 + reg], v);
        }
    // col sums: reduce across the 4 lane-groups
    #pragma unroll
    for (int ni = 0; ni < 4; ++ni) {
        float v = cp[ni];
        v += __shfl_xor(v, 16); v += __shfl_xor(v, 32);
        if (g == 0) atomicAdd(&colsum[j0 + wc * 64 + ni * 16 + cl], v);
    }
}

__global__ __launch_bounds__(1024) void finalize(const float* __restrict__ rowsum,
                                                 const float* __restrict__ colsum,
                                                 const float* __restrict__ diag,
                                                 float* __restrict__ out) {
    float s = 0.f;
    for (int i = threadIdx.x; i < NROWS; i += 1024)
        s += logf(rowsum[i]) + logf(colsum[i]) - 2.0f * diag[i];
    __shared__ float red[16];
    int lane = threadIdx.x & 63, wv = threadIdx.x >> 6;
    for (int m = 1; m < 64; m <<= 1) s += __shfl_xor(s, m);
    if (lane == 0) red[wv] = s;
    __syncthreads();
    if (threadIdx.x == 0) {
        float t = 0.f;
        #pragma unroll
        for (int k = 0; k < 16; ++k) t += red[k];
        out[0] = t / (2.0f * NROWS);
    }
}

extern "C" void kernel_launch(void* const* d_in, const int* in_sizes, int n_in,
                              void* d_out, int out_size, void* d_ws, size_t ws_size,
                              hipStream_t stream) {
    const float* audio = (const float*)d_in[0];
    const float* text  = (const float*)d_in[1];
    // labels (d_in[2]) are arange(N) -> diagonal; not needed.
    float* out = (float*)d_out;

    char* ws = (char*)d_ws;
    const size_t BF = (size_t)NROWS * DDIM * sizeof(unsigned short);  // 8 MiB
    unsigned short* Abf = (unsigned short*)ws;
    unsigned short* Bbf = (unsigned short*)(ws + BF);
    float* a2     = (float*)(ws + 2 * BF);
    float* b2     = a2 + NROWS;
    float* rowsum = b2 + NROWS;
    float* colsum = rowsum + NROWS;
    float* diag   = colsum + NROWS;

    hipMemsetAsync(rowsum, 0, 2 * NROWS * sizeof(float), stream);
    convert_norms<<<NROWS / 4, 256, 0, stream>>>(audio, Abf, a2);
    convert_norms<<<NROWS / 4, 256, 0, stream>>>(text,  Bbf, b2);
    hyper_gemm<<<dim3(NROWS / BN, NROWS / BM), 256, 0, stream>>>(Abf, Bbf, a2, b2, rowsum, colsum, diag);
    finalize<<<1, 1024, 0, stream>>>(rowsum, colsum, diag, out);
}

// Round 4
// 265.259 us; speedup vs baseline: 1.1510x; 1.1510x over previous
//
#include <hip/hip_runtime.h>
#include <hip/hip_bf16.h>

// HyperbolicContrastiveLoss: N=8192, D=512, f32 in, scalar f32 out.
// loss = (1/2N) * sum_i [ log(sum_j exp(sim_ij)) + log(sum_i exp(sim_ij)) - 2*sim_ii ]
// Key identity: exp(sim) = exp(-arccosh(arg)) = 1/(arg + sqrt(arg^2-1)) — no exp/log
// needed in the O(N^2) inner loop; log only on the N diagonal terms.

#define NROWS 8192
#define DDIM  512
#define BM 128
#define BN 128
#define BK 64

typedef __attribute__((ext_vector_type(8))) short bf16x8;
typedef __attribute__((ext_vector_type(4))) float f32x4;

constexpr float EPSF = 1e-10f;

#define GLOAD_LDS16(g, l)                                                        \
    __builtin_amdgcn_global_load_lds(                                            \
        (const __attribute__((address_space(1))) void*)(g),                      \
        (__attribute__((address_space(3))) void*)(l), 16, 0, 0)

__device__ inline unsigned short f2bf(float f) {
    union { float f; unsigned int u; } x; x.f = f;
    unsigned int r = x.u + 0x7fffu + ((x.u >> 16) & 1u);  // RNE
    return (unsigned short)(r >> 16);
}

// One wave per row: convert f32 -> bf16 and compute row squared norm.
// blockIdx.y selects audio (0) or text (1).
__global__ __launch_bounds__(256) void convert_norms(const float* __restrict__ audio,
                                                     const float* __restrict__ text,
                                                     unsigned short* __restrict__ Ab,
                                                     unsigned short* __restrict__ Bb,
                                                     float* __restrict__ a2,
                                                     float* __restrict__ b2) {
    const float* src = blockIdx.y ? text : audio;
    unsigned short* dst = blockIdx.y ? Bb : Ab;
    float* nrm = blockIdx.y ? b2 : a2;

    int wave = threadIdx.x >> 6;
    int lane = threadIdx.x & 63;
    int row  = blockIdx.x * 4 + wave;
    const float* r = src + (size_t)row * DDIM + lane * 8;
    float4 v0 = *(const float4*)(r);
    float4 v1 = *(const float4*)(r + 4);
    float ss = v0.x*v0.x + v0.y*v0.y + v0.z*v0.z + v0.w*v0.w
             + v1.x*v1.x + v1.y*v1.y + v1.z*v1.z + v1.w*v1.w;
    unsigned short u[8];
    u[0]=f2bf(v0.x); u[1]=f2bf(v0.y); u[2]=f2bf(v0.z); u[3]=f2bf(v0.w);
    u[4]=f2bf(v1.x); u[5]=f2bf(v1.y); u[6]=f2bf(v1.z); u[7]=f2bf(v1.w);
    *(uint4*)(dst + (size_t)row * DDIM + lane * 8) = *(const uint4*)u;
    for (int m = 1; m < 64; m <<= 1) ss += __shfl_xor(ss, m);
    if (lane == 0) nrm[row] = ss;
}

// 128x128 tile MFMA GEMM (A@B^T) with fused hyperbolic-sim epilogue.
// Staging: global_load_lds (linear LDS dest) with pre-swizzled per-lane global
// source; reads apply the same XOR -> conflict-free ds_read_b128.
__global__ __launch_bounds__(256) void hyper_gemm(
    const unsigned short* __restrict__ A, const unsigned short* __restrict__ B,
    const float* __restrict__ a2, const float* __restrict__ b2,
    float* __restrict__ rowsum, float* __restrict__ colsum,
    float* __restrict__ diag) {

    __shared__ unsigned short As[BM * BK];
    __shared__ unsigned short Bs[BN * BK];

    const int tid  = threadIdx.x;
    const int lane = tid & 63;
    const int w    = tid >> 6;
    const int wr   = w >> 1, wc = w & 1;
    const int i0 = blockIdx.y * BM;
    const int j0 = blockIdx.x * BN;
    const int g  = lane >> 4;      // 0..3
    const int cl = lane & 15;      // 0..15

    // ---- staging addresses: wave w stages rows [32w, 32w+32) of each tile,
    // as 4 chunks of 8 rows. Linear LDS dest; global col pre-swizzled.
    const int srow = lane >> 3;                       // 0..7 (row within chunk)
    const int scol = ((lane & 7) ^ srow) * 8;         // swizzled col (elements)
    const char* aP[4]; const char* bP[4];
    char* aL[4]; char* bL[4];
    #pragma unroll
    for (int c = 0; c < 4; ++c) {
        int row = w * 32 + c * 8 + srow;
        aP[c] = (const char*)(A + (size_t)(i0 + row) * DDIM + scol);
        bP[c] = (const char*)(B + (size_t)(j0 + row) * DDIM + scol);
        aL[c] = (char*)As + w * 4096 + c * 1024;
        bL[c] = (char*)Bs + w * 4096 + c * 1024;
    }

    // ---- fragment ds_read byte offsets (constant across k0; tile reused in place)
    int offA[4][2], offB[4][2];
    #pragma unroll
    for (int mi = 0; mi < 4; ++mi) {
        int rowA = wr * 64 + mi * 16 + cl;
        int rowB = wc * 64 + mi * 16 + cl;
        #pragma unroll
        for (int kh = 0; kh < 2; ++kh) {
            int cb = (kh * 32 + g * 8) * 2;
            offA[mi][kh] = rowA * 128 + (cb ^ ((rowA & 7) << 4));
            offB[mi][kh] = rowB * 128 + (cb ^ ((rowB & 7) << 4));
        }
    }

    f32x4 acc[4][4];
    #pragma unroll
    for (int mi = 0; mi < 4; ++mi)
        #pragma unroll
        for (int ni = 0; ni < 4; ++ni)
            acc[mi][ni] = (f32x4)0.0f;

    for (int k0 = 0; k0 < DDIM; k0 += BK) {
        __syncthreads();   // previous tile's reads done before overwrite
        #pragma unroll
        for (int c = 0; c < 4; ++c) {
            GLOAD_LDS16(aP[c], aL[c]);
            GLOAD_LDS16(bP[c], bL[c]);
            aP[c] += BK * 2;
            bP[c] += BK * 2;
        }
        __syncthreads();   // compiler drains vmcnt(0) before barrier

        #pragma unroll
        for (int kh = 0; kh < 2; ++kh) {
            bf16x8 af[4], bfr[4];
            #pragma unroll
            for (int mi = 0; mi < 4; ++mi)
                af[mi] = *(const bf16x8*)((const char*)As + offA[mi][kh]);
            #pragma unroll
            for (int ni = 0; ni < 4; ++ni)
                bfr[ni] = *(const bf16x8*)((const char*)Bs + offB[ni][kh]);
            #pragma unroll
            for (int mi = 0; mi < 4; ++mi)
                #pragma unroll
                for (int ni = 0; ni < 4; ++ni)
                    acc[mi][ni] = __builtin_amdgcn_mfma_f32_16x16x32_bf16(af[mi], bfr[ni], acc[mi][ni], 0, 0, 0);
        }
    }

    // ---- epilogue: e = 1/(arg + sqrt(arg^2-1)); accumulate row/col partials.
    float B2c[4], fb[4];
    #pragma unroll
    for (int ni = 0; ni < 4; ++ni) {
        float B2 = b2[j0 + wc * 64 + ni * 16 + cl];
        B2c[ni] = B2;
        fb[ni] = __builtin_amdgcn_rcpf(1.0f - fminf(B2, 1.0f - EPSF));
    }

    float cp[4] = {0.f, 0.f, 0.f, 0.f};
    #pragma unroll
    for (int mi = 0; mi < 4; ++mi) {
        #pragma unroll
        for (int reg = 0; reg < 4; ++reg) {
            int   gi  = i0 + wr * 64 + mi * 16 + g * 4 + reg;
            float A2  = a2[gi];
            float fa  = 2.0f * __builtin_amdgcn_rcpf(1.0f - fminf(A2, 1.0f - EPSF));
            float rsum = 0.f;
            #pragma unroll
            for (int ni = 0; ni < 4; ++ni) {
                float dot  = acc[mi][ni][reg];
                float diff = fmaf(-2.0f, dot, A2 + B2c[ni]);
                float arg  = fmaf(diff * fa, fb[ni], 1.0f);
                arg = fmaxf(arg, 1.0f + EPSF);
                float sq = sqrtf(fmaf(arg, arg, -1.0f));
                float z  = arg + sq;
                float e  = __builtin_amdgcn_rcpf(z);
                rsum += e;
                cp[ni] += e;
                int gj = j0 + wc * 64 + ni * 16 + cl;
                if (gi == gj) diag[gi] = -__logf(z);
            }
            // row partial: reduce across the 16 lanes of this row's group
            float v = rsum;
            v += __shfl_xor(v, 1); v += __shfl_xor(v, 2);
            v += __shfl_xor(v, 4); v += __shfl_xor(v, 8);
            if (cl == 0) atomicAdd(&rowsum[gi], v);
        }
    }
    #pragma unroll
    for (int ni = 0; ni < 4; ++ni) {
        float v = cp[ni];
        v += __shfl_xor(v, 16); v += __shfl_xor(v, 32);
        if (g == 0) atomicAdd(&colsum[j0 + wc * 64 + ni * 16 + cl], v);
    }
}

__global__ __launch_bounds__(256) void finalize(const float* __restrict__ rowsum,
                                                const float* __restrict__ colsum,
                                                const float* __restrict__ diag,
                                                float* __restrict__ out) {
    int i = blockIdx.x * 256 + threadIdx.x;
    float s = logf(rowsum[i]) + logf(colsum[i]) - 2.0f * diag[i];
    #pragma unroll
    for (int m = 1; m < 64; m <<= 1) s += __shfl_xor(s, m);
    if ((threadIdx.x & 63) == 0)
        atomicAdd(out, s * (1.0f / (2.0f * NROWS)));
}

extern "C" void kernel_launch(void* const* d_in, const int* in_sizes, int n_in,
                              void* d_out, int out_size, void* d_ws, size_t ws_size,
                              hipStream_t stream) {
    const float* audio = (const float*)d_in[0];
    const float* text  = (const float*)d_in[1];
    // labels (d_in[2]) are arange(N) -> diagonal; not needed.
    float* out = (float*)d_out;

    char* ws = (char*)d_ws;
    const size_t BF = (size_t)NROWS * DDIM * sizeof(unsigned short);  // 8 MiB
    unsigned short* Abf = (unsigned short*)ws;
    unsigned short* Bbf = (unsigned short*)(ws + BF);
    float* a2     = (float*)(ws + 2 * BF);
    float* b2     = a2 + NROWS;
    float* rowsum = b2 + NROWS;
    float* colsum = rowsum + NROWS;
    float* diag   = colsum + NROWS;

    hipMemsetAsync(rowsum, 0, 2 * NROWS * sizeof(float), stream);
    hipMemsetAsync(out, 0, sizeof(float), stream);
    convert_norms<<<dim3(NROWS / 4, 2), 256, 0, stream>>>(audio, text, Abf, Bbf, a2, b2);
    hyper_gemm<<<dim3(NROWS / BN, NROWS / BM), 256, 0, stream>>>(Abf, Bbf, a2, b2, rowsum, colsum, diag);
    finalize<<<NROWS / 256, 256, 0, stream>>>(rowsum, colsum, diag, out);
}

// Round 5
// 226.999 us; speedup vs baseline: 1.3450x; 1.1685x over previous
//
#include <hip/hip_runtime.h>
#include <hip/hip_bf16.h>

// HyperbolicContrastiveLoss: N=8192, D=512, f32 in, scalar f32 out.
// loss = (1/2N) * sum_i [ log(sum_j exp(sim_ij)) + log(sum_i exp(sim_ij)) - 2*sim_ii ]
// exp(sim) = exp(-arccosh(arg)) = arg - sqrt(arg^2-1)  (exact; (arg+s)(arg-s)=1)
// -> O(N^2) inner loop has NO log/exp/rcp; diag (sim_ii) computed f32-precise in
// the convert kernel. K-loop: 2-phase double-buffered global_load_lds pipeline.

#define NROWS 8192
#define DDIM  512
#define BM 128
#define BN 128
#define BK 64
#define NT (DDIM / BK)   // 8 K-steps

typedef __attribute__((ext_vector_type(8))) short bf16x8;
typedef __attribute__((ext_vector_type(4))) float f32x4;

constexpr float EPSF = 1e-10f;

#define GLOAD_LDS16(g, l)                                                        \
    __builtin_amdgcn_global_load_lds(                                            \
        (const __attribute__((address_space(1))) void*)(g),                      \
        (__attribute__((address_space(3))) void*)(l), 16, 0, 0)

__device__ inline unsigned short f2bf(float f) {
    union { float f; unsigned int u; } x; x.f = f;
    unsigned int r = x.u + 0x7fffu + ((x.u >> 16) & 1u);  // RNE
    return (unsigned short)(r >> 16);
}

// One wave per row pair: convert audio+text row r to bf16, row norms, and the
// f32-precise diagonal sim_ii = -arccosh(1 + 2*(a2+b2-2*dot)/denom).
__global__ __launch_bounds__(256) void convert_norms(const float* __restrict__ audio,
                                                     const float* __restrict__ text,
                                                     unsigned short* __restrict__ Ab,
                                                     unsigned short* __restrict__ Bb,
                                                     float* __restrict__ a2,
                                                     float* __restrict__ b2,
                                                     float* __restrict__ diag) {
    int wave = threadIdx.x >> 6;
    int lane = threadIdx.x & 63;
    int row  = blockIdx.x * 4 + wave;
    const float* ra = audio + (size_t)row * DDIM + lane * 8;
    const float* rt = text  + (size_t)row * DDIM + lane * 8;
    float4 a0 = *(const float4*)(ra), a1 = *(const float4*)(ra + 4);
    float4 t0 = *(const float4*)(rt), t1 = *(const float4*)(rt + 4);

    float sa = a0.x*a0.x + a0.y*a0.y + a0.z*a0.z + a0.w*a0.w
             + a1.x*a1.x + a1.y*a1.y + a1.z*a1.z + a1.w*a1.w;
    float st = t0.x*t0.x + t0.y*t0.y + t0.z*t0.z + t0.w*t0.w
             + t1.x*t1.x + t1.y*t1.y + t1.z*t1.z + t1.w*t1.w;
    float dt = a0.x*t0.x + a0.y*t0.y + a0.z*t0.z + a0.w*t0.w
             + a1.x*t1.x + a1.y*t1.y + a1.z*t1.z + a1.w*t1.w;

    unsigned short ua[8], ut[8];
    ua[0]=f2bf(a0.x); ua[1]=f2bf(a0.y); ua[2]=f2bf(a0.z); ua[3]=f2bf(a0.w);
    ua[4]=f2bf(a1.x); ua[5]=f2bf(a1.y); ua[6]=f2bf(a1.z); ua[7]=f2bf(a1.w);
    ut[0]=f2bf(t0.x); ut[1]=f2bf(t0.y); ut[2]=f2bf(t0.z); ut[3]=f2bf(t0.w);
    ut[4]=f2bf(t1.x); ut[5]=f2bf(t1.y); ut[6]=f2bf(t1.z); ut[7]=f2bf(t1.w);
    *(uint4*)(Ab + (size_t)row * DDIM + lane * 8) = *(const uint4*)ua;
    *(uint4*)(Bb + (size_t)row * DDIM + lane * 8) = *(const uint4*)ut;

    #pragma unroll
    for (int m = 1; m < 64; m <<= 1) {
        sa += __shfl_xor(sa, m);
        st += __shfl_xor(st, m);
        dt += __shfl_xor(dt, m);
    }
    if (lane == 0) {
        a2[row] = sa;
        b2[row] = st;
        float a2c  = fminf(sa, 1.0f - EPSF);
        float b2c  = fminf(st, 1.0f - EPSF);
        float diff = sa + st - 2.0f * dt;
        float den  = fmaxf((1.0f - a2c) * (1.0f - b2c), EPSF);
        float arg  = fmaxf(1.0f + 2.0f * diff / den, 1.0f + EPSF);
        diag[row]  = -logf(arg + sqrtf(arg * arg - 1.0f));
    }
}

// 128x128 tile MFMA GEMM (A@B^T) with fused hyperbolic-sim epilogue.
// 2-phase double-buffered global_load_lds pipeline, one barrier per K-step.
__global__ __launch_bounds__(256) void hyper_gemm(
    const unsigned short* __restrict__ A, const unsigned short* __restrict__ B,
    const float* __restrict__ a2, const float* __restrict__ b2,
    float* __restrict__ rowsum, float* __restrict__ colsum) {

    __shared__ char lds[2 * 32768];   // [buf][A 16K | B 16K]

    const int tid  = threadIdx.x;
    const int lane = tid & 63;
    const int w    = tid >> 6;
    const int wr   = w >> 1, wc = w & 1;

    // XCD-aware bijective swizzle (grid = 4096, 4096 % 8 == 0):
    // XCD x handles an 8-row stripe by in [8x, 8x+8); within the stripe, 8
    // consecutive dispatch slots share one B-panel (bx) -> L2-hot.
    const int bid = blockIdx.x;
    const int idx = bid >> 3;
    const int by  = (bid & 7) * 8 + (idx & 7);
    const int bx  = idx >> 3;
    const int i0 = by * BM;
    const int j0 = bx * BN;

    const int g  = lane >> 4;      // 0..3
    const int cl = lane & 15;      // 0..15

    // ---- staging: wave w stages rows [32w,32w+32) of each tile as 4 chunks of
    // 8 rows (64 lanes x 16B = 1KB). Linear LDS dest; global col pre-swizzled.
    const int srow = lane >> 3;                   // 0..7
    const int scol = ((lane & 7) ^ srow) * 8;     // swizzled col (elements)
    const char* aP[4]; const char* bP[4]; int ldsOff[4];
    #pragma unroll
    for (int c = 0; c < 4; ++c) {
        int row = w * 32 + c * 8 + srow;
        aP[c] = (const char*)(A + (size_t)(i0 + row) * DDIM + scol);
        bP[c] = (const char*)(B + (size_t)(j0 + row) * DDIM + scol);
        ldsOff[c] = w * 4096 + c * 1024;
    }

    // ---- fragment ds_read byte offsets (B offsets include +16384 base)
    int offA[4][2], offB[4][2];
    #pragma unroll
    for (int mi = 0; mi < 4; ++mi) {
        int rowA = wr * 64 + mi * 16 + cl;
        int rowB = wc * 64 + mi * 16 + cl;
        #pragma unroll
        for (int kh = 0; kh < 2; ++kh) {
            int cb = (kh * 32 + g * 8) * 2;
            offA[mi][kh] = rowA * 128 + (cb ^ ((rowA & 7) << 4));
            offB[mi][kh] = 16384 + rowB * 128 + (cb ^ ((rowB & 7) << 4));
        }
    }

    f32x4 acc[4][4];
    #pragma unroll
    for (int mi = 0; mi < 4; ++mi)
        #pragma unroll
        for (int ni = 0; ni < 4; ++ni)
            acc[mi][ni] = (f32x4)0.0f;

#define STAGE(buf, t)                                                     \
    do {                                                                  \
        _Pragma("unroll")                                                 \
        for (int c = 0; c < 4; ++c) {                                     \
            GLOAD_LDS16(aP[c] + (t) * (BK * 2),                           \
                        lds + (buf) * 32768 + ldsOff[c]);                 \
            GLOAD_LDS16(bP[c] + (t) * (BK * 2),                           \
                        lds + (buf) * 32768 + 16384 + ldsOff[c]);         \
        }                                                                 \
    } while (0)

#define COMPUTE(buf)                                                      \
    do {                                                                  \
        _Pragma("unroll")                                                 \
        for (int kh = 0; kh < 2; ++kh) {                                  \
            bf16x8 af[4], bfr[4];                                         \
            _Pragma("unroll")                                             \
            for (int mi = 0; mi < 4; ++mi)                                \
                af[mi] = *(const bf16x8*)(lds + (buf) * 32768 + offA[mi][kh]); \
            _Pragma("unroll")                                             \
            for (int ni = 0; ni < 4; ++ni)                                \
                bfr[ni] = *(const bf16x8*)(lds + (buf) * 32768 + offB[ni][kh]); \
            _Pragma("unroll")                                             \
            for (int mi = 0; mi < 4; ++mi)                                \
                _Pragma("unroll")                                         \
                for (int ni = 0; ni < 4; ++ni)                            \
                    acc[mi][ni] = __builtin_amdgcn_mfma_f32_16x16x32_bf16(\
                        af[mi], bfr[ni], acc[mi][ni], 0, 0, 0);           \
        }                                                                 \
    } while (0)

    STAGE(0, 0);
    __syncthreads();                       // tile 0 resident
    #pragma unroll
    for (int t = 0; t < NT; ++t) {
        if (t + 1 < NT) STAGE((t + 1) & 1, t + 1);   // prefetch next tile
        COMPUTE(t & 1);
        if (t + 1 < NT) __syncthreads();   // drains prefetch + lds reads
    }
#undef STAGE
#undef COMPUTE

    // ---- epilogue: e = arg - sqrt(arg^2-1); accumulate row/col partials.
    float B2c[4], fb[4];
    #pragma unroll
    for (int ni = 0; ni < 4; ++ni) {
        float B2 = b2[j0 + wc * 64 + ni * 16 + cl];
        B2c[ni] = B2;
        fb[ni] = __builtin_amdgcn_rcpf(1.0f - fminf(B2, 1.0f - EPSF));
    }

    float cp[4] = {0.f, 0.f, 0.f, 0.f};
    #pragma unroll
    for (int mi = 0; mi < 4; ++mi) {
        #pragma unroll
        for (int reg = 0; reg < 4; ++reg) {
            int   gi  = i0 + wr * 64 + mi * 16 + g * 4 + reg;
            float A2  = a2[gi];
            float fa  = 2.0f * __builtin_amdgcn_rcpf(1.0f - fminf(A2, 1.0f - EPSF));
            float rsum = 0.f;
            #pragma unroll
            for (int ni = 0; ni < 4; ++ni) {
                float dot  = acc[mi][ni][reg];
                float diff = fmaf(-2.0f, dot, A2 + B2c[ni]);
                float arg  = fmaf(diff * fa, fb[ni], 1.0f);
                arg = fmaxf(arg, 1.0f);
                float sq = sqrtf(fmaf(arg, arg, -1.0f));
                float e  = arg - sq;      // exp(-arccosh(arg)), exact
                rsum += e;
                cp[ni] += e;
            }
            float v = rsum;
            v += __shfl_xor(v, 1); v += __shfl_xor(v, 2);
            v += __shfl_xor(v, 4); v += __shfl_xor(v, 8);
            if (cl == 0) atomicAdd(&rowsum[gi], v);
        }
    }
    #pragma unroll
    for (int ni = 0; ni < 4; ++ni) {
        float v = cp[ni];
        v += __shfl_xor(v, 16); v += __shfl_xor(v, 32);
        if (g == 0) atomicAdd(&colsum[j0 + wc * 64 + ni * 16 + cl], v);
    }
}

__global__ __launch_bounds__(256) void finalize(const float* __restrict__ rowsum,
                                                const float* __restrict__ colsum,
                                                const float* __restrict__ diag,
                                                float* __restrict__ out) {
    int i = blockIdx.x * 256 + threadIdx.x;
    float s = logf(rowsum[i]) + logf(colsum[i]) - 2.0f * diag[i];
    #pragma unroll
    for (int m = 1; m < 64; m <<= 1) s += __shfl_xor(s, m);
    if ((threadIdx.x & 63) == 0)
        atomicAdd(out, s * (1.0f / (2.0f * NROWS)));
}

extern "C" void kernel_launch(void* const* d_in, const int* in_sizes, int n_in,
                              void* d_out, int out_size, void* d_ws, size_t ws_size,
                              hipStream_t stream) {
    const float* audio = (const float*)d_in[0];
    const float* text  = (const float*)d_in[1];
    // labels (d_in[2]) are arange(N) -> diagonal; not needed.
    float* out = (float*)d_out;

    char* ws = (char*)d_ws;
    const size_t BF = (size_t)NROWS * DDIM * sizeof(unsigned short);  // 8 MiB
    unsigned short* Abf = (unsigned short*)ws;
    unsigned short* Bbf = (unsigned short*)(ws + BF);
    float* a2     = (float*)(ws + 2 * BF);
    float* b2     = a2 + NROWS;
    float* rowsum = b2 + NROWS;
    float* colsum = rowsum + NROWS;
    float* diag   = colsum + NROWS;

    hipMemsetAsync(rowsum, 0, 2 * NROWS * sizeof(float), stream);
    hipMemsetAsync(out, 0, sizeof(float), stream);
    convert_norms<<<NROWS / 4, 256, 0, stream>>>(audio, text, Abf, Bbf, a2, b2, diag);
    hyper_gemm<<<(NROWS / BM) * (NROWS / BN), 256, 0, stream>>>(Abf, Bbf, a2, b2, rowsum, colsum);
    finalize<<<NROWS / 256, 256, 0, stream>>>(rowsum, colsum, diag, out);
}